// Round 10
// baseline (919.279 us; speedup 1.0000x reference)
//
#include <hip/hip_runtime.h>
#include <stdint.h>

// GNN: 2-layer GCN + skip + classifier head. All fp32 in/out; edge_index int32.
// N=100000, E=1600000, F=H=128, OUT=40.
//
// Round-20: fix round-19's scratch disaster. ((float*)&vec)[k] address-taken
// register arrays -> local memory -> 1.65 GB scratch traffic, final_k 560us.
// Same 16-k-step group hoisting, but ALL element access via .x/.y/.z/.w member
// syntax (compile-time, register-resident). Everything else = round-18 (356.5us).
// Aggregate frozen: 68.5us = L2-miss-fill floor (203 MB compulsory per-XCD lines).

#define HID 128
#define OUTD 40
#define BSH 8                 // 256 nodes per bucket
#define BCAP 6144             // LDS colbuf entries per bucket (mean ~4350)
#define CAPSH 13              // slack bucket capacity = 8192 pair slots
#define EPB 8192              // edges per scatter block
#define NBMAX 512

typedef __attribute__((ext_vector_type(8))) short short8;
typedef __attribute__((ext_vector_type(4))) float f32x4;
typedef __attribute__((ext_vector_type(2))) float f32x2;

__device__ inline uint16_t f32_to_bf16(float f) {
    uint32_t u = __float_as_uint(f);
    uint32_t r = u + 0x7FFFu + ((u >> 16) & 1u);
    return (uint16_t)(r >> 16);
}
__device__ inline uint32_t pack_bf16x2(float lo, float hi) {
    return (uint32_t)f32_to_bf16(lo) | ((uint32_t)f32_to_bf16(hi) << 16);
}
__device__ inline float bf_lo(uint32_t u) { return __uint_as_float(u << 16); }
__device__ inline float bf_hi(uint32_t u) { return __uint_as_float(u & 0xFFFF0000u); }
// {even col, odd col} of one packed dword — f32x2 so the backend can use v_pk_add_f32
__device__ inline f32x2 up2(uint32_t u) {
    f32x2 r;
    r.x = __uint_as_float(u << 16);
    r.y = __uint_as_float(u & 0xFFFF0000u);
    return r;
}

// ---------------- scatter (+W swizzle on spare blocks) ----------------
// blocks [0,nEB): scatter edges into slack buckets pairbuf[b*8192 + 0..cnt_b).
// pcur (zeroed) is the per-bucket allocator.
// blocks [nEB, nEB+16): W swizzle fp32 -> bf16 B-fragment order:
// Wsw[((ct*4+ks)*64+lane)*8+j] = bf16(W[(ks*32+(lane>>4)*8+j)*128 + ct*16+(lane&15)])
__global__ __launch_bounds__(256) void gnn_scatter_wsw_k(const int* __restrict__ edges,
                                                         int* __restrict__ pcur,
                                                         uint32_t* __restrict__ pairbuf,
                                                         const float* __restrict__ W1,
                                                         const float* __restrict__ W2,
                                                         uint16_t* __restrict__ w1s,
                                                         uint16_t* __restrict__ w2s,
                                                         int E, int NB, int nEB) {
    if ((int)blockIdx.x >= nEB) {
        int wb = blockIdx.x - nEB;             // 0..15
        const float* W = (wb < 8) ? W1 : W2;
        uint16_t* O = (wb < 8) ? w1s : w2s;
        int t = (wb & 7) * 256 + threadIdx.x;  // 0..2047
        int lane = t & 63;
        int ksct = t >> 6;                     // ct*4+ks
        int nn = (ksct >> 2) * 16 + (lane & 15);
        int k0 = (ksct & 3) * 32 + (lane >> 4) * 8;
        uint32_t d[4];
#pragma unroll
        for (int j = 0; j < 4; ++j)
            d[j] = pack_bf16x2(W[(size_t)(k0 + 2 * j) * HID + nn],
                               W[(size_t)(k0 + 2 * j + 1) * HID + nn]);
        *(uint4*)(O + (size_t)t * 8) = make_uint4(d[0], d[1], d[2], d[3]);
        return;
    }
    __shared__ int hist[NBMAX];
    int e0 = blockIdx.x * EPB;
    int e1 = min(E, e0 + EPB);
    for (int b = threadIdx.x; b < NB; b += 256) hist[b] = 0;
    __syncthreads();
    for (int e = e0 + threadIdx.x; e < e1; e += 256)
        atomicAdd(&hist[edges[E + e] >> BSH], 1);
    __syncthreads();
    for (int b = threadIdx.x; b < NB; b += 256) {
        int c = hist[b];
        hist[b] = (c > 0) ? (atomicAdd(&pcur[b], c) + (b << CAPSH)) : 0;
    }
    __syncthreads();
    for (int e = e0 + threadIdx.x; e < e1; e += 256) {
        int src = edges[e];
        int dst = edges[E + e];
        int pos = atomicAdd(&hist[dst >> BSH], 1);
        pairbuf[pos] = ((uint32_t)(dst & 255) << 24) | (uint32_t)src;
    }
}

// per bucket: self-computed prefix over pcur -> segbeg; LDS degree histogram ->
// 256-scan -> rowptr/dinv; self-loop + pair placement into colbuf (or colidx direct).
__global__ __launch_bounds__(256) void gnn_build_csr_k(const uint32_t* __restrict__ pairbuf,
                                                       const int* __restrict__ pcur,
                                                       int* __restrict__ rowptr,
                                                       float* __restrict__ dinv,
                                                       int* __restrict__ colidx, int n) {
    __shared__ int red[256];
    __shared__ int deg[256];     // histogram, then reused as per-node cursor
    __shared__ int scn[256];
    __shared__ int colbuf[BCAP];
    int b = blockIdx.x;
    int t = threadIdx.x;

    // prefix: segbeg = sum_{i<b} pcur[i] + b*256 (earlier buckets are all full)
    int part = 0;
    for (int i = t; i < b; i += 256) part += pcur[i];
    red[t] = part;
    __syncthreads();
    for (int off = 128; off > 0; off >>= 1) {
        if (t < off) red[t] += red[t + off];
        __syncthreads();
    }
    const int segbeg = red[0] + (b << BSH);

    int nb0 = b << BSH;
    int nb1 = min(n, nb0 + 256);
    int nn = nb1 - nb0;
    int npairs = pcur[b];
    int seglen = npairs + nn;
    int pairbeg = b << CAPSH;    // slack layout

    deg[t] = 0;
    __syncthreads();
    for (int p = t; p < npairs; p += 256)
        atomicAdd(&deg[pairbuf[pairbeg + p] >> 24], 1);
    __syncthreads();

    int d = (t < nn) ? deg[t] : 0;
    int v = (t < nn) ? d + 1 : 0;
    scn[t] = v;
    __syncthreads();
    for (int off = 1; off < 256; off <<= 1) {
        int x = 0;
        if (t >= off) x = scn[t - off];
        __syncthreads();
        if (t >= off) scn[t] += x;
        __syncthreads();
    }
    int rel = scn[t] - v;                 // exclusive prefix
    if (t < nn) {
        rowptr[nb0 + t + 1] = segbeg + scn[t];
        dinv[nb0 + t] = rsqrtf((float)(d + 1));
    }
    if (t == 0) rowptr[nb0] = segbeg;
    __syncthreads();

    if (seglen <= BCAP) {
        if (t < nn) {
            colbuf[rel] = nb0 + t;        // self loop
            deg[t] = rel + 1;
        }
        __syncthreads();
        for (int p = t; p < npairs; p += 256) {
            uint32_t pr = pairbuf[pairbeg + p];
            int pos = atomicAdd(&deg[pr >> 24], 1);
            colbuf[pos] = (int)(pr & 0xFFFFFFu);
        }
        __syncthreads();
        for (int i = t; i < seglen; i += 256)
            colidx[segbeg + i] = colbuf[i];
    } else {
        if (t < nn) {
            colidx[segbeg + rel] = nb0 + t;
            deg[t] = rel + 1;
        }
        __syncthreads();
        for (int p = t; p < npairs; p += 256) {
            uint32_t pr = pairbuf[pairbeg + p];
            int pos = atomicAdd(&deg[pr >> 24], 1);
            colidx[segbeg + pos] = (int)(pr & 0xFFFFFFu);
        }
    }
}

// ---------------- MFMA GEMM [n,128] @ [128,128], row-scaled by dinv -> bf16 h' ----------------
// 256 threads = 4 waves x 16 rows. Per wave: 8 col-tiles x 4 K-steps of 16x16x32 bf16.
// A-frag straight from global; ABF16 picks fp32/bf16 A. D: col=lane&15, row=quad*4+reg.

template <bool ABF16>
__global__ __launch_bounds__(256) void gnn_gemm_mfma_k(const void* __restrict__ Aptr,
                                                       const uint32_t* __restrict__ Wsw,
                                                       const float* __restrict__ dinv,
                                                       uint16_t* __restrict__ outh, int n) {
    int wave = threadIdx.x >> 6;
    int lane = threadIdx.x & 63;
    int m = lane & 15;
    int q = lane >> 4;
    int row0 = blockIdx.x * 64 + wave * 16;
    int arow = min(row0 + m, n - 1);

    f32x4 acc[8];
#pragma unroll
    for (int i = 0; i < 8; ++i) acc[i] = (f32x4){0.f, 0.f, 0.f, 0.f};

#pragma unroll
    for (int ks = 0; ks < 4; ++ks) {
        short8 a;
        if (ABF16) {
            const uint16_t* Ab = (const uint16_t*)Aptr;
            uint4 u = *(const uint4*)(Ab + (size_t)arow * HID + ks * 32 + q * 8);
            a = __builtin_bit_cast(short8, u);
        } else {
            const float* Af = (const float*)Aptr + (size_t)arow * HID + ks * 32 + q * 8;
            uint4 u0 = *(const uint4*)(Af);
            uint4 u1 = *(const uint4*)(Af + 4);
            uint4 p;
            p.x = pack_bf16x2(__uint_as_float(u0.x), __uint_as_float(u0.y));
            p.y = pack_bf16x2(__uint_as_float(u0.z), __uint_as_float(u0.w));
            p.z = pack_bf16x2(__uint_as_float(u1.x), __uint_as_float(u1.y));
            p.w = pack_bf16x2(__uint_as_float(u1.z), __uint_as_float(u1.w));
            a = __builtin_bit_cast(short8, p);
        }
#pragma unroll
        for (int ct = 0; ct < 8; ++ct) {
            uint4 bu = *(const uint4*)(Wsw + ((size_t)(ct * 4 + ks) * 64 + lane) * 4);
            short8 bfr = __builtin_bit_cast(short8, bu);
            acc[ct] = __builtin_amdgcn_mfma_f32_16x16x32_bf16(a, bfr, acc[ct], 0, 0, 0);
        }
    }

    float dv[4];
#pragma unroll
    for (int r = 0; r < 4; ++r) dv[r] = dinv[min(row0 + q * 4 + r, n - 1)];

#pragma unroll
    for (int ct = 0; ct < 8; ++ct) {
#pragma unroll
        for (int r = 0; r < 4; ++r) {
            int rr = row0 + q * 4 + r;
            if (rr < n)
                outh[(size_t)rr * HID + ct * 16 + m] = f32_to_bf16(acc[ct][r] * dv[r]);
        }
    }
}

// ---------------- aggregation: one wave per node, grouped dwordx4 gather ----------------
// 64 lanes = 4 edge-groups x 16 lanes; f32x2 packed accumulate (v_pk_add_f32);
// xor-butterfly reduce; lanes 0..31 bf16 epilogue (in-place skip safe).

__global__ __launch_bounds__(256) void gnn_aggregate_k(const uint4* __restrict__ h4,
                                const int* __restrict__ rowptr,
                                const int* __restrict__ colidx, const float* __restrict__ dinv,
                                const float* __restrict__ bias,
                                const uint16_t* __restrict__ skipb,
                                uint16_t* __restrict__ outsh, int n) {
    int node = blockIdx.x * 4 + (threadIdx.x >> 6);
    if (node >= n) return;
    int lane = threadIdx.x & 63;
    int g = lane >> 4;
    int sub = lane & 15;
    int beg = rowptr[node];
    int end = rowptr[node + 1];
    f32x2 acc2[4];
#pragma unroll
    for (int i = 0; i < 4; ++i) acc2[i] = (f32x2){0.f, 0.f};
    int e = beg;
    for (; e + 15 < end; e += 16) {
        int j0 = colidx[e + g];
        int j1 = colidx[e + 4 + g];
        int j2 = colidx[e + 8 + g];
        int j3 = colidx[e + 12 + g];
        uint4 u0 = h4[(size_t)j0 * 16 + sub];
        uint4 u1 = h4[(size_t)j1 * 16 + sub];
        uint4 u2 = h4[(size_t)j2 * 16 + sub];
        uint4 u3 = h4[(size_t)j3 * 16 + sub];
        acc2[0] += up2(u0.x); acc2[1] += up2(u0.y); acc2[2] += up2(u0.z); acc2[3] += up2(u0.w);
        acc2[0] += up2(u1.x); acc2[1] += up2(u1.y); acc2[2] += up2(u1.z); acc2[3] += up2(u1.w);
        acc2[0] += up2(u2.x); acc2[1] += up2(u2.y); acc2[2] += up2(u2.z); acc2[3] += up2(u2.w);
        acc2[0] += up2(u3.x); acc2[1] += up2(u3.y); acc2[2] += up2(u3.z); acc2[3] += up2(u3.w);
    }
    for (; e + 3 < end; e += 4) {
        int j = colidx[e + g];
        uint4 u = h4[(size_t)j * 16 + sub];
        acc2[0] += up2(u.x); acc2[1] += up2(u.y); acc2[2] += up2(u.z); acc2[3] += up2(u.w);
    }
    if (g < end - e) {
        int j = colidx[e + g];
        uint4 u = h4[(size_t)j * 16 + sub];
        acc2[0] += up2(u.x); acc2[1] += up2(u.y); acc2[2] += up2(u.z); acc2[3] += up2(u.w);
    }
    float a8[8];
#pragma unroll
    for (int i = 0; i < 4; ++i) { a8[2 * i] = acc2[i].x; a8[2 * i + 1] = acc2[i].y; }
#pragma unroll
    for (int k = 0; k < 8; ++k) {
        a8[k] += __shfl_xor(a8[k], 16, 64);
        a8[k] += __shfl_xor(a8[k], 32, 64);
    }
    if (lane < 32) {
        int half = lane >> 4;
        int col = sub * 8 + half * 4;
        float di = dinv[node];
        float4 bv = *(const float4*)(bias + col);
        float o0 = fmaxf(di * a8[half * 4 + 0] + bv.x, 0.0f);
        float o1 = fmaxf(di * a8[half * 4 + 1] + bv.y, 0.0f);
        float o2 = fmaxf(di * a8[half * 4 + 2] + bv.z, 0.0f);
        float o3 = fmaxf(di * a8[half * 4 + 3] + bv.w, 0.0f);
        if (skipb) {
            uint2 sv = *(const uint2*)(skipb + (size_t)node * HID + col);
            o0 += bf_lo(sv.x); o1 += bf_hi(sv.x);
            o2 += bf_lo(sv.y); o3 += bf_hi(sv.y);
        }
        uint2 sh;
        sh.x = pack_bf16x2(o0, o1);
        sh.y = pack_bf16x2(o2, o3);
        *(uint2*)(outsh + (size_t)node * HID + col) = sh;
    }
}

// ---------------- final: bf16 sum[n,128] @ Wc[128,40] + bc -> fp32 ----------------
// 16-k-step group hoisting (8 LDS b128 + 16 wc float4 per group), all element
// access via .x/.y/.z/.w — NO pointer casts into vector temporaries (round-19's
// ((float*)&v)[k] forced the arrays to scratch: 1.65 GB local-memory traffic).

__global__ __launch_bounds__(320) void gnn_final_k(const uint16_t* __restrict__ sumh,
                                                   const float* __restrict__ wc,
                                                   const float* __restrict__ bc,
                                                   float* __restrict__ out, int n) {
    __shared__ float a[64 * HID];  // 32 KB, float4 block (r, c4) at r*32 + (c4 ^ (r&7))
    const int tx = threadIdx.x % 10;
    const int ty = threadIdx.x / 10;
    const int row0 = blockIdx.x * 64;

    {
        const uint4* S8 = (const uint4*)sumh;  // 8 bf16 per uint4; 16 per row
        float4* s4 = (float4*)a;
        for (int idx = threadIdx.x; idx < 64 * 16; idx += 320) {
            int r = idx >> 4, c8 = idx & 15;
            uint4 v = make_uint4(0u, 0u, 0u, 0u);
            if (row0 + r < n) v = S8[(size_t)(row0 + r) * 16 + c8];
            float4 f0 = make_float4(bf_lo(v.x), bf_hi(v.x), bf_lo(v.y), bf_hi(v.y));
            float4 f1 = make_float4(bf_lo(v.z), bf_hi(v.z), bf_lo(v.w), bf_hi(v.w));
            s4[r * 32 + ((2 * c8) ^ (r & 7))] = f0;
            s4[r * 32 + ((2 * c8 + 1) ^ (r & 7))] = f1;
        }
    }
    __syncthreads();

    float acc00, acc01, acc02, acc03, acc10, acc11, acc12, acc13;
    {
        float b0 = bc[tx * 4], b1 = bc[tx * 4 + 1], b2 = bc[tx * 4 + 2], b3 = bc[tx * 4 + 3];
        acc00 = b0; acc01 = b1; acc02 = b2; acc03 = b3;
        acc10 = b0; acc11 = b1; acc12 = b2; acc13 = b3;
    }
    const float* wp = wc + tx * 4;
    const float4* s4 = (const float4*)a;
    const int r0 = ty * 2, r1 = ty * 2 + 1;

#pragma unroll
    for (int kg = 0; kg < 8; ++kg) {      // 8 groups x 16 k-steps
        float4 a00 = s4[r0 * 32 + ((kg * 4 + 0) ^ (r0 & 7))];
        float4 a01 = s4[r0 * 32 + ((kg * 4 + 1) ^ (r0 & 7))];
        float4 a02 = s4[r0 * 32 + ((kg * 4 + 2) ^ (r0 & 7))];
        float4 a03 = s4[r0 * 32 + ((kg * 4 + 3) ^ (r0 & 7))];
        float4 a10 = s4[r1 * 32 + ((kg * 4 + 0) ^ (r1 & 7))];
        float4 a11 = s4[r1 * 32 + ((kg * 4 + 1) ^ (r1 & 7))];
        float4 a12 = s4[r1 * 32 + ((kg * 4 + 2) ^ (r1 & 7))];
        float4 a13 = s4[r1 * 32 + ((kg * 4 + 3) ^ (r1 & 7))];
        float4 w0, w1, w2, w3;
#pragma unroll
        for (int u = 0; u < 4; ++u) {
            const float* wb = wp + (size_t)(kg * 16 + u * 4) * OUTD;
            w0 = *(const float4*)(wb);
            w1 = *(const float4*)(wb + OUTD);
            w2 = *(const float4*)(wb + 2 * OUTD);
            w3 = *(const float4*)(wb + 3 * OUTD);
            float4 av0 = (u == 0) ? a00 : (u == 1) ? a01 : (u == 2) ? a02 : a03;
            float4 av1 = (u == 0) ? a10 : (u == 1) ? a11 : (u == 2) ? a12 : a13;
            acc00 += av0.x * w0.x + av0.y * w1.x + av0.z * w2.x + av0.w * w3.x;
            acc01 += av0.x * w0.y + av0.y * w1.y + av0.z * w2.y + av0.w * w3.y;
            acc02 += av0.x * w0.z + av0.y * w1.z + av0.z * w2.z + av0.w * w3.z;
            acc03 += av0.x * w0.w + av0.y * w1.w + av0.z * w2.w + av0.w * w3.w;
            acc10 += av1.x * w0.x + av1.y * w1.x + av1.z * w2.x + av1.w * w3.x;
            acc11 += av1.x * w0.y + av1.y * w1.y + av1.z * w2.y + av1.w * w3.y;
            acc12 += av1.x * w0.z + av1.y * w1.z + av1.z * w2.z + av1.w * w3.z;
            acc13 += av1.x * w0.w + av1.y * w1.w + av1.z * w2.w + av1.w * w3.w;
        }
    }

    {
        int row = row0 + r0;
        if (row < n)
            *(float4*)(out + (size_t)row * OUTD + tx * 4) = make_float4(acc00, acc01, acc02, acc03);
        row = row0 + r1;
        if (row < n)
            *(float4*)(out + (size_t)row * OUTD + tx * 4) = make_float4(acc10, acc11, acc12, acc13);
    }
}

// ---------------- launch ----------------

extern "C" void kernel_launch(void* const* d_in, const int* in_sizes, int n_in,
                              void* d_out, int out_size, void* d_ws, size_t ws_size,
                              hipStream_t stream) {
    const int N = in_sizes[0] / HID;   // 100000
    const int E = in_sizes[7] / 2;     // 1600000

    const float* x  = (const float*)d_in[0];
    const float* W1 = (const float*)d_in[1];
    const float* b1 = (const float*)d_in[2];
    const float* W2 = (const float*)d_in[3];
    const float* b2 = (const float*)d_in[4];
    const float* Wc = (const float*)d_in[5];
    const float* bc = (const float*)d_in[6];
    const int* edges = (const int*)d_in[7];
    float* out = (float*)d_out;

    // workspace carve-up (256B aligned)
    char* w = (char*)d_ws;
    auto alloc = [&](size_t bytes) -> char* {
        char* p = w;
        w += (bytes + 255) & ~(size_t)255;
        return p;
    };
    uint16_t* hbuf  = (uint16_t*)alloc((size_t)N * HID * 2);  // h' bf16; pairbuf aliases this
    uint16_t* bufBh = (uint16_t*)alloc((size_t)N * HID * 2);  // bf16 out1, then bf16 sum
    int*   rowptr  = (int*)alloc((size_t)(N + 1) * 4);
    int*   colidx  = (int*)alloc((size_t)(E + N) * 4);
    float* dinv    = (float*)alloc((size_t)N * 4);
    int*   pcur    = (int*)alloc(512 * 4);
    uint16_t* w1s  = (uint16_t*)alloc(HID * HID * 2);
    uint16_t* w2s  = (uint16_t*)alloc(HID * HID * 2);

    uint32_t* pairbuf = (uint32_t*)hbuf;  // dead until gemm1; NB*8192*4 = 12.8MB <= 25.6MB

    const int NB = (N + 255) >> BSH;   // buckets (391)
    const int nEB = (E + EPB - 1) / EPB;

    hipMemsetAsync(pcur, 0, 512 * 4, stream);

    gnn_scatter_wsw_k<<<nEB + 16, 256, 0, stream>>>(edges, pcur, pairbuf,
                                                    W1, W2, w1s, w2s, E, NB, nEB);
    gnn_build_csr_k<<<NB, 256, 0, stream>>>(pairbuf, pcur, rowptr, dinv, colidx, N);

    // layer 1: h1' = bf16(dinv * (x @ W1)) ; bufBh = bf16(relu(dinv*agg(h1') + b1))
    gnn_gemm_mfma_k<false><<<(N + 63) / 64, 256, 0, stream>>>(x, (const uint32_t*)w1s, dinv, hbuf, N);
    gnn_aggregate_k<<<(N + 3) / 4, 256, 0, stream>>>((const uint4*)hbuf, rowptr, colidx,
                                                     dinv, b1, nullptr, bufBh, N);
    // layer 2: h2' = bf16(dinv * (out1 @ W2)) ; bufBh = bf16(relu(...) + out1) in place
    gnn_gemm_mfma_k<true><<<(N + 63) / 64, 256, 0, stream>>>(bufBh, (const uint32_t*)w2s, dinv, hbuf, N);
    gnn_aggregate_k<<<(N + 3) / 4, 256, 0, stream>>>((const uint4*)hbuf, rowptr, colidx,
                                                     dinv, b2, bufBh, bufBh, N);
    // head
    gnn_final_k<<<(N + 63) / 64, 320, 0, stream>>>(bufBh, Wc, bc, out, N);
}

// Round 11
// 324.042 us; speedup vs baseline: 2.8369x; 2.8369x over previous
//
#include <hip/hip_runtime.h>
#include <stdint.h>

// GNN: 2-layer GCN + skip + classifier head. All fp32 in/out; edge_index int32.
// N=100000, E=1600000, F=H=128, OUT=40.
//
// Round-21: final_k rebuilt on the PROVEN MFMA-GEMM skeleton (rounds 19/20's fp32
// k-loop hit compiler scratch pathologies: 1.6-2.1 GB spill traffic). sum[n,128]bf16
// @ Wc[128,40] via 3 col-tiles (pad 48) x 4 K-steps of 16x16x32 bf16. Precision:
// split-bf16 Wc (hi=bf16(w), lo=bf16(w-hi)), two MFMAs into one fp32 acc -> error
// ~2^-17, absmax unchanged. Wc swizzle = 3 tail blocks on scatter_wsw.
// Everything else identical to round-18 (356.5us). Aggregate frozen: 68.5us =
// L2-miss-fill floor (203 MB compulsory per-XCD lines at 4 line-req/edge).

#define HID 128
#define OUTD 40
#define BSH 8                 // 256 nodes per bucket
#define BCAP 6144             // LDS colbuf entries per bucket (mean ~4350)
#define CAPSH 13              // slack bucket capacity = 8192 pair slots
#define EPB 8192              // edges per scatter block
#define NBMAX 512

typedef __attribute__((ext_vector_type(8))) short short8;
typedef __attribute__((ext_vector_type(4))) float f32x4;
typedef __attribute__((ext_vector_type(2))) float f32x2;

__device__ inline uint16_t f32_to_bf16(float f) {
    uint32_t u = __float_as_uint(f);
    uint32_t r = u + 0x7FFFu + ((u >> 16) & 1u);
    return (uint16_t)(r >> 16);
}
__device__ inline uint32_t pack_bf16x2(float lo, float hi) {
    return (uint32_t)f32_to_bf16(lo) | ((uint32_t)f32_to_bf16(hi) << 16);
}
__device__ inline float bf_lo(uint32_t u) { return __uint_as_float(u << 16); }
__device__ inline float bf_hi(uint32_t u) { return __uint_as_float(u & 0xFFFF0000u); }
__device__ inline float bf16_val(uint16_t h) { return __uint_as_float((uint32_t)h << 16); }
// {even col, odd col} of one packed dword — f32x2 so the backend can use v_pk_add_f32
__device__ inline f32x2 up2(uint32_t u) {
    f32x2 r;
    r.x = __uint_as_float(u << 16);
    r.y = __uint_as_float(u & 0xFFFF0000u);
    return r;
}

// ---------------- scatter (+W/Wc swizzle on spare blocks) ----------------
// blocks [0,nEB): scatter edges into slack buckets pairbuf[b*8192 + 0..cnt_b).
// blocks [nEB, nEB+16): W1/W2 swizzle fp32 -> bf16 B-fragment order:
//   Wsw[((ct*4+ks)*64+lane)*8+j] = bf16(W[(ks*32+(lane>>4)*8+j)*128 + ct*16+(lane&15)])
// blocks [nEB+16, nEB+19): Wc split-bf16 swizzle (ct = wb-16, cols >= 40 zero):
//   hi at wcs[(ct*256+t)*8+j], lo at wcs[6144 + (ct*256+t)*8+j]
__global__ __launch_bounds__(256) void gnn_scatter_wsw_k(const int* __restrict__ edges,
                                                         int* __restrict__ pcur,
                                                         uint32_t* __restrict__ pairbuf,
                                                         const float* __restrict__ W1,
                                                         const float* __restrict__ W2,
                                                         const float* __restrict__ Wc,
                                                         uint16_t* __restrict__ w1s,
                                                         uint16_t* __restrict__ w2s,
                                                         uint16_t* __restrict__ wcs,
                                                         int E, int NB, int nEB) {
    if ((int)blockIdx.x >= nEB + 16) {
        int ct = blockIdx.x - nEB - 16;        // 0..2
        int t = threadIdx.x;                   // = ks*64 + lane
        int lane = t & 63;
        int ks = t >> 6;
        int col = ct * 16 + (lane & 15);
        int k0 = ks * 32 + (lane >> 4) * 8;
        uint32_t dh[4], dl[4];
#pragma unroll
        for (int j = 0; j < 4; ++j) {
            float wa = (col < OUTD) ? Wc[(size_t)(k0 + 2 * j) * OUTD + col] : 0.f;
            float wb = (col < OUTD) ? Wc[(size_t)(k0 + 2 * j + 1) * OUTD + col] : 0.f;
            uint16_t ha = f32_to_bf16(wa), hb = f32_to_bf16(wb);
            float la = wa - bf16_val(ha), lb = wb - bf16_val(hb);
            dh[j] = (uint32_t)ha | ((uint32_t)hb << 16);
            dl[j] = pack_bf16x2(la, lb);
        }
        size_t ent = (size_t)(ct * 256 + t) * 8;
        *(uint4*)(wcs + ent) = make_uint4(dh[0], dh[1], dh[2], dh[3]);
        *(uint4*)(wcs + 6144 + ent) = make_uint4(dl[0], dl[1], dl[2], dl[3]);
        return;
    }
    if ((int)blockIdx.x >= nEB) {
        int wb = blockIdx.x - nEB;             // 0..15
        const float* W = (wb < 8) ? W1 : W2;
        uint16_t* O = (wb < 8) ? w1s : w2s;
        int t = (wb & 7) * 256 + threadIdx.x;  // 0..2047
        int lane = t & 63;
        int ksct = t >> 6;                     // ct*4+ks
        int nn = (ksct >> 2) * 16 + (lane & 15);
        int k0 = (ksct & 3) * 32 + (lane >> 4) * 8;
        uint32_t d[4];
#pragma unroll
        for (int j = 0; j < 4; ++j)
            d[j] = pack_bf16x2(W[(size_t)(k0 + 2 * j) * HID + nn],
                               W[(size_t)(k0 + 2 * j + 1) * HID + nn]);
        *(uint4*)(O + (size_t)t * 8) = make_uint4(d[0], d[1], d[2], d[3]);
        return;
    }
    __shared__ int hist[NBMAX];
    int e0 = blockIdx.x * EPB;
    int e1 = min(E, e0 + EPB);
    for (int b = threadIdx.x; b < NB; b += 256) hist[b] = 0;
    __syncthreads();
    for (int e = e0 + threadIdx.x; e < e1; e += 256)
        atomicAdd(&hist[edges[E + e] >> BSH], 1);
    __syncthreads();
    for (int b = threadIdx.x; b < NB; b += 256) {
        int c = hist[b];
        hist[b] = (c > 0) ? (atomicAdd(&pcur[b], c) + (b << CAPSH)) : 0;
    }
    __syncthreads();
    for (int e = e0 + threadIdx.x; e < e1; e += 256) {
        int src = edges[e];
        int dst = edges[E + e];
        int pos = atomicAdd(&hist[dst >> BSH], 1);
        pairbuf[pos] = ((uint32_t)(dst & 255) << 24) | (uint32_t)src;
    }
}

// per bucket: self-computed prefix over pcur -> segbeg; LDS degree histogram ->
// 256-scan -> rowptr/dinv; self-loop + pair placement into colbuf (or colidx direct).
__global__ __launch_bounds__(256) void gnn_build_csr_k(const uint32_t* __restrict__ pairbuf,
                                                       const int* __restrict__ pcur,
                                                       int* __restrict__ rowptr,
                                                       float* __restrict__ dinv,
                                                       int* __restrict__ colidx, int n) {
    __shared__ int red[256];
    __shared__ int deg[256];     // histogram, then reused as per-node cursor
    __shared__ int scn[256];
    __shared__ int colbuf[BCAP];
    int b = blockIdx.x;
    int t = threadIdx.x;

    // prefix: segbeg = sum_{i<b} pcur[i] + b*256 (earlier buckets are all full)
    int part = 0;
    for (int i = t; i < b; i += 256) part += pcur[i];
    red[t] = part;
    __syncthreads();
    for (int off = 128; off > 0; off >>= 1) {
        if (t < off) red[t] += red[t + off];
        __syncthreads();
    }
    const int segbeg = red[0] + (b << BSH);

    int nb0 = b << BSH;
    int nb1 = min(n, nb0 + 256);
    int nn = nb1 - nb0;
    int npairs = pcur[b];
    int seglen = npairs + nn;
    int pairbeg = b << CAPSH;    // slack layout

    deg[t] = 0;
    __syncthreads();
    for (int p = t; p < npairs; p += 256)
        atomicAdd(&deg[pairbuf[pairbeg + p] >> 24], 1);
    __syncthreads();

    int d = (t < nn) ? deg[t] : 0;
    int v = (t < nn) ? d + 1 : 0;
    scn[t] = v;
    __syncthreads();
    for (int off = 1; off < 256; off <<= 1) {
        int x = 0;
        if (t >= off) x = scn[t - off];
        __syncthreads();
        if (t >= off) scn[t] += x;
        __syncthreads();
    }
    int rel = scn[t] - v;                 // exclusive prefix
    if (t < nn) {
        rowptr[nb0 + t + 1] = segbeg + scn[t];
        dinv[nb0 + t] = rsqrtf((float)(d + 1));
    }
    if (t == 0) rowptr[nb0] = segbeg;
    __syncthreads();

    if (seglen <= BCAP) {
        if (t < nn) {
            colbuf[rel] = nb0 + t;        // self loop
            deg[t] = rel + 1;
        }
        __syncthreads();
        for (int p = t; p < npairs; p += 256) {
            uint32_t pr = pairbuf[pairbeg + p];
            int pos = atomicAdd(&deg[pr >> 24], 1);
            colbuf[pos] = (int)(pr & 0xFFFFFFu);
        }
        __syncthreads();
        for (int i = t; i < seglen; i += 256)
            colidx[segbeg + i] = colbuf[i];
    } else {
        if (t < nn) {
            colidx[segbeg + rel] = nb0 + t;
            deg[t] = rel + 1;
        }
        __syncthreads();
        for (int p = t; p < npairs; p += 256) {
            uint32_t pr = pairbuf[pairbeg + p];
            int pos = atomicAdd(&deg[pr >> 24], 1);
            colidx[segbeg + pos] = (int)(pr & 0xFFFFFFu);
        }
    }
}

// ---------------- MFMA GEMM [n,128] @ [128,128], row-scaled by dinv -> bf16 h' ----------------
// 256 threads = 4 waves x 16 rows. Per wave: 8 col-tiles x 4 K-steps of 16x16x32 bf16.
// A-frag straight from global; ABF16 picks fp32/bf16 A. D: col=lane&15, row=quad*4+reg.

template <bool ABF16>
__global__ __launch_bounds__(256) void gnn_gemm_mfma_k(const void* __restrict__ Aptr,
                                                       const uint32_t* __restrict__ Wsw,
                                                       const float* __restrict__ dinv,
                                                       uint16_t* __restrict__ outh, int n) {
    int wave = threadIdx.x >> 6;
    int lane = threadIdx.x & 63;
    int m = lane & 15;
    int q = lane >> 4;
    int row0 = blockIdx.x * 64 + wave * 16;
    int arow = min(row0 + m, n - 1);

    f32x4 acc[8];
#pragma unroll
    for (int i = 0; i < 8; ++i) acc[i] = (f32x4){0.f, 0.f, 0.f, 0.f};

#pragma unroll
    for (int ks = 0; ks < 4; ++ks) {
        short8 a;
        if (ABF16) {
            const uint16_t* Ab = (const uint16_t*)Aptr;
            uint4 u = *(const uint4*)(Ab + (size_t)arow * HID + ks * 32 + q * 8);
            a = __builtin_bit_cast(short8, u);
        } else {
            const float* Af = (const float*)Aptr + (size_t)arow * HID + ks * 32 + q * 8;
            uint4 u0 = *(const uint4*)(Af);
            uint4 u1 = *(const uint4*)(Af + 4);
            uint4 p;
            p.x = pack_bf16x2(__uint_as_float(u0.x), __uint_as_float(u0.y));
            p.y = pack_bf16x2(__uint_as_float(u0.z), __uint_as_float(u0.w));
            p.z = pack_bf16x2(__uint_as_float(u1.x), __uint_as_float(u1.y));
            p.w = pack_bf16x2(__uint_as_float(u1.z), __uint_as_float(u1.w));
            a = __builtin_bit_cast(short8, p);
        }
#pragma unroll
        for (int ct = 0; ct < 8; ++ct) {
            uint4 bu = *(const uint4*)(Wsw + ((size_t)(ct * 4 + ks) * 64 + lane) * 4);
            short8 bfr = __builtin_bit_cast(short8, bu);
            acc[ct] = __builtin_amdgcn_mfma_f32_16x16x32_bf16(a, bfr, acc[ct], 0, 0, 0);
        }
    }

    float dv[4];
#pragma unroll
    for (int r = 0; r < 4; ++r) dv[r] = dinv[min(row0 + q * 4 + r, n - 1)];

#pragma unroll
    for (int ct = 0; ct < 8; ++ct) {
#pragma unroll
        for (int r = 0; r < 4; ++r) {
            int rr = row0 + q * 4 + r;
            if (rr < n)
                outh[(size_t)rr * HID + ct * 16 + m] = f32_to_bf16(acc[ct][r] * dv[r]);
        }
    }
}

// ---------------- aggregation: one wave per node, grouped dwordx4 gather ----------------
// 64 lanes = 4 edge-groups x 16 lanes; f32x2 packed accumulate (v_pk_add_f32);
// xor-butterfly reduce; lanes 0..31 bf16 epilogue (in-place skip safe).

__global__ __launch_bounds__(256) void gnn_aggregate_k(const uint4* __restrict__ h4,
                                const int* __restrict__ rowptr,
                                const int* __restrict__ colidx, const float* __restrict__ dinv,
                                const float* __restrict__ bias,
                                const uint16_t* __restrict__ skipb,
                                uint16_t* __restrict__ outsh, int n) {
    int node = blockIdx.x * 4 + (threadIdx.x >> 6);
    if (node >= n) return;
    int lane = threadIdx.x & 63;
    int g = lane >> 4;
    int sub = lane & 15;
    int beg = rowptr[node];
    int end = rowptr[node + 1];
    f32x2 acc2[4];
#pragma unroll
    for (int i = 0; i < 4; ++i) acc2[i] = (f32x2){0.f, 0.f};
    int e = beg;
    for (; e + 15 < end; e += 16) {
        int j0 = colidx[e + g];
        int j1 = colidx[e + 4 + g];
        int j2 = colidx[e + 8 + g];
        int j3 = colidx[e + 12 + g];
        uint4 u0 = h4[(size_t)j0 * 16 + sub];
        uint4 u1 = h4[(size_t)j1 * 16 + sub];
        uint4 u2 = h4[(size_t)j2 * 16 + sub];
        uint4 u3 = h4[(size_t)j3 * 16 + sub];
        acc2[0] += up2(u0.x); acc2[1] += up2(u0.y); acc2[2] += up2(u0.z); acc2[3] += up2(u0.w);
        acc2[0] += up2(u1.x); acc2[1] += up2(u1.y); acc2[2] += up2(u1.z); acc2[3] += up2(u1.w);
        acc2[0] += up2(u2.x); acc2[1] += up2(u2.y); acc2[2] += up2(u2.z); acc2[3] += up2(u2.w);
        acc2[0] += up2(u3.x); acc2[1] += up2(u3.y); acc2[2] += up2(u3.z); acc2[3] += up2(u3.w);
    }
    for (; e + 3 < end; e += 4) {
        int j = colidx[e + g];
        uint4 u = h4[(size_t)j * 16 + sub];
        acc2[0] += up2(u.x); acc2[1] += up2(u.y); acc2[2] += up2(u.z); acc2[3] += up2(u.w);
    }
    if (g < end - e) {
        int j = colidx[e + g];
        uint4 u = h4[(size_t)j * 16 + sub];
        acc2[0] += up2(u.x); acc2[1] += up2(u.y); acc2[2] += up2(u.z); acc2[3] += up2(u.w);
    }
    float a8[8];
#pragma unroll
    for (int i = 0; i < 4; ++i) { a8[2 * i] = acc2[i].x; a8[2 * i + 1] = acc2[i].y; }
#pragma unroll
    for (int k = 0; k < 8; ++k) {
        a8[k] += __shfl_xor(a8[k], 16, 64);
        a8[k] += __shfl_xor(a8[k], 32, 64);
    }
    if (lane < 32) {
        int half = lane >> 4;
        int col = sub * 8 + half * 4;
        float di = dinv[node];
        float4 bv = *(const float4*)(bias + col);
        float o0 = fmaxf(di * a8[half * 4 + 0] + bv.x, 0.0f);
        float o1 = fmaxf(di * a8[half * 4 + 1] + bv.y, 0.0f);
        float o2 = fmaxf(di * a8[half * 4 + 2] + bv.z, 0.0f);
        float o3 = fmaxf(di * a8[half * 4 + 3] + bv.w, 0.0f);
        if (skipb) {
            uint2 sv = *(const uint2*)(skipb + (size_t)node * HID + col);
            o0 += bf_lo(sv.x); o1 += bf_hi(sv.x);
            o2 += bf_lo(sv.y); o3 += bf_hi(sv.y);
        }
        uint2 sh;
        sh.x = pack_bf16x2(o0, o1);
        sh.y = pack_bf16x2(o2, o3);
        *(uint2*)(outsh + (size_t)node * HID + col) = sh;
    }
}

// ---------------- final: bf16 sum[n,128] @ Wc[128,40] + bc -> fp32 (MFMA) ----------------
// Clone of the gemm skeleton: 4 waves x 16 rows, 3 col-tiles (48 cols, >=40 zero),
// 4 K-steps. Split-bf16 Wc: acc += A*Wc_hi + A*Wc_lo (both MFMA, one fp32 acc) ->
// error ~2^-17, no precision loss vs fp32 FMA. 24 MFMA/wave, no LDS, no big k-loop.

__global__ __launch_bounds__(256) void gnn_final_k(const uint16_t* __restrict__ sumh,
                                                   const uint32_t* __restrict__ Wcs,
                                                   const float* __restrict__ bc,
                                                   float* __restrict__ out, int n) {
    int wave = threadIdx.x >> 6;
    int lane = threadIdx.x & 63;
    int m = lane & 15;
    int q = lane >> 4;
    int row0 = blockIdx.x * 64 + wave * 16;
    int arow = min(row0 + m, n - 1);

    f32x4 acc[3];
#pragma unroll
    for (int i = 0; i < 3; ++i) acc[i] = (f32x4){0.f, 0.f, 0.f, 0.f};

#pragma unroll
    for (int ks = 0; ks < 4; ++ks) {
        uint4 u = *(const uint4*)(sumh + (size_t)arow * HID + ks * 32 + q * 8);
        short8 a = __builtin_bit_cast(short8, u);
#pragma unroll
        for (int ct = 0; ct < 3; ++ct) {
            uint4 bh = *(const uint4*)(Wcs + ((size_t)(ct * 4 + ks) * 64 + lane) * 4);
            uint4 bl = *(const uint4*)(Wcs + 3072 + ((size_t)(ct * 4 + ks) * 64 + lane) * 4);
            short8 fh = __builtin_bit_cast(short8, bh);
            short8 fl = __builtin_bit_cast(short8, bl);
            acc[ct] = __builtin_amdgcn_mfma_f32_16x16x32_bf16(a, fh, acc[ct], 0, 0, 0);
            acc[ct] = __builtin_amdgcn_mfma_f32_16x16x32_bf16(a, fl, acc[ct], 0, 0, 0);
        }
    }

#pragma unroll
    for (int ct = 0; ct < 3; ++ct) {
        int col = ct * 16 + m;
        if (col < OUTD) {
            float bcv = bc[col];
#pragma unroll
            for (int r = 0; r < 4; ++r) {
                int rr = row0 + q * 4 + r;
                if (rr < n)
                    out[(size_t)rr * OUTD + col] = acc[ct][r] + bcv;
            }
        }
    }
}

// ---------------- launch ----------------

extern "C" void kernel_launch(void* const* d_in, const int* in_sizes, int n_in,
                              void* d_out, int out_size, void* d_ws, size_t ws_size,
                              hipStream_t stream) {
    const int N = in_sizes[0] / HID;   // 100000
    const int E = in_sizes[7] / 2;     // 1600000

    const float* x  = (const float*)d_in[0];
    const float* W1 = (const float*)d_in[1];
    const float* b1 = (const float*)d_in[2];
    const float* W2 = (const float*)d_in[3];
    const float* b2 = (const float*)d_in[4];
    const float* Wc = (const float*)d_in[5];
    const float* bc = (const float*)d_in[6];
    const int* edges = (const int*)d_in[7];
    float* out = (float*)d_out;

    // workspace carve-up (256B aligned)
    char* w = (char*)d_ws;
    auto alloc = [&](size_t bytes) -> char* {
        char* p = w;
        w += (bytes + 255) & ~(size_t)255;
        return p;
    };
    uint16_t* hbuf  = (uint16_t*)alloc((size_t)N * HID * 2);  // h' bf16; pairbuf aliases this
    uint16_t* bufBh = (uint16_t*)alloc((size_t)N * HID * 2);  // bf16 out1, then bf16 sum
    int*   rowptr  = (int*)alloc((size_t)(N + 1) * 4);
    int*   colidx  = (int*)alloc((size_t)(E + N) * 4);
    float* dinv    = (float*)alloc((size_t)N * 4);
    int*   pcur    = (int*)alloc(512 * 4);
    uint16_t* w1s  = (uint16_t*)alloc(HID * HID * 2);
    uint16_t* w2s  = (uint16_t*)alloc(HID * HID * 2);
    uint16_t* wcs  = (uint16_t*)alloc(2 * 6144 * 2);          // Wc hi+lo fragments (24 KB)

    uint32_t* pairbuf = (uint32_t*)hbuf;  // dead until gemm1; NB*8192*4 = 12.8MB <= 25.6MB

    const int NB = (N + 255) >> BSH;   // buckets (391)
    const int nEB = (E + EPB - 1) / EPB;

    hipMemsetAsync(pcur, 0, 512 * 4, stream);

    gnn_scatter_wsw_k<<<nEB + 19, 256, 0, stream>>>(edges, pcur, pairbuf,
                                                    W1, W2, Wc, w1s, w2s, wcs, E, NB, nEB);
    gnn_build_csr_k<<<NB, 256, 0, stream>>>(pairbuf, pcur, rowptr, dinv, colidx, N);

    // layer 1: h1' = bf16(dinv * (x @ W1)) ; bufBh = bf16(relu(dinv*agg(h1') + b1))
    gnn_gemm_mfma_k<false><<<(N + 63) / 64, 256, 0, stream>>>(x, (const uint32_t*)w1s, dinv, hbuf, N);
    gnn_aggregate_k<<<(N + 3) / 4, 256, 0, stream>>>((const uint4*)hbuf, rowptr, colidx,
                                                     dinv, b1, nullptr, bufBh, N);
    // layer 2: h2' = bf16(dinv * (out1 @ W2)) ; bufBh = bf16(relu(...) + out1) in place
    gnn_gemm_mfma_k<true><<<(N + 63) / 64, 256, 0, stream>>>(bufBh, (const uint32_t*)w2s, dinv, hbuf, N);
    gnn_aggregate_k<<<(N + 3) / 4, 256, 0, stream>>>((const uint4*)hbuf, rowptr, colidx,
                                                     dinv, b2, bufBh, bufBh, N);
    // head: out = sum @ Wc + bc via split-bf16 MFMA
    gnn_final_k<<<(N + 63) / 64, 256, 0, stream>>>(bufBh, (const uint32_t*)wcs, bc, out, N);
}